// Round 3
// baseline (1030.238 us; speedup 1.0000x reference)
//
#include <hip/hip_runtime.h>
#include <stdint.h>

// ---------------- problem constants ----------------
#define NBI 4          // batch
#define RRI 512        // rois per image
#define NROI 2048      // NBI*RRI
#define CFEAT 256
#define HF 50
#define WF 50
#define NCLS 91
#define DIN 12544      // 256*7*7
#define H1 1024
#define NHEAD 455      // 91 + 4*91
#define TOPK 2048
#define DETS 100

// ---------------- workspace layout (bytes) ----------------
#define O_FEATT   0ull                    // 10,240,000  [4][50][50][256] f32
#define O_POOLED  10240000ull             // 102,760,448 [2048][12544] f32
#define O_PART    113000448ull            // 33,554,432  [4][2048][1024] f32 (also x2 later)
#define O_X1      0ull                    // reuses featT region (8,388,608)
#define O_X2      113000448ull            // aliases PART p0 (in-place reduce)
#define O_HEAD    146554880ull            // 3,727,360   [2048][455] f32
#define O_PBOX    150282240ull            // 2,949,120   [2048][90][4] f32 (clipped boxes)
#define O_KEYS    153231360ull            // 524,288     [4][16384] u64
#define O_NMSBOX  153755648ull            // 131,072     [4][2048][4] f32 (offset boxes)
#define O_OUTBOX  153886720ull            // 131,072     [4][2048][4] f32 (clipped boxes)
#define O_SCORE   154017792ull            // 32,768      [4][2048] f32
#define O_LABEL   154050560ull            // 32,768      [4][2048] f32
#define O_MASK    154083328ull            // 2,097,152   [4][2048][64] u32
#define O_CNT     156180480ull            // 256         [4] u32
#define O_END     156180736ull

#define BBOX_CLIP_F 4.135166556742356f    // float(log(1000/16))

// ---------------- zero init (d_out, keys, counters) ----------------
__global__ void k_zero(float* __restrict__ out, unsigned* __restrict__ keys32,
                       unsigned* __restrict__ cnt) {
  int i = blockIdx.x * 256 + threadIdx.x;
  if (i < 2400) out[i] = 0.0f;
  if (i < 131072) keys32[i] = 0u;      // 4*16384 u64 = 131072 u32
  if (i < 64) cnt[i] = 0u;
}

// ---------------- features [B,C,H,W] -> [B,H,W,C] ----------------
__global__ void k_transpose(const float* __restrict__ f, float* __restrict__ ft) {
  int bhw = blockIdx.x;                  // b*2500 + h*50 + w  (grid 10000)
  int c = threadIdx.x;                   // 256
  int b = bhw / 2500, hw = bhw - b * 2500;
  ft[(size_t)bhw * 256 + c] = f[((size_t)b * 256 + c) * 2500 + hw];
}

// ---------------- RoI align: one block per roi ----------------
__global__ __launch_bounds__(256) void k_roialign(const float* __restrict__ ft,
                                                  const float* __restrict__ props,
                                                  float* __restrict__ pooled) {
  __shared__ float pool[DIN];
  __shared__ float lyA[7], lxA[7];
  __shared__ int y0A[7], y1A[7], x0A[7], x1A[7];
  int roi = blockIdx.x;
  int b = roi >> 9;
  const float* p = props + (size_t)roi * 4;
  float x1s = p[0] * 0.0625f, y1s = p[1] * 0.0625f;
  float x2s = p[2] * 0.0625f, y2s = p[3] * 0.0625f;
  float bh = (y2s - y1s) / 7.0f;
  float bw = (x2s - x1s) / 7.0f;
  int t = threadIdx.x;
  if (t < 7) {
    float y = y1s + ((float)t + 0.5f) * bh;
    y = fminf(fmaxf(y, 0.0f), 49.0f);
    float y0 = floorf(y);
    int y0i = (int)y0;
    y0A[t] = y0i; y1A[t] = min(y0i + 1, 49); lyA[t] = y - y0;
  } else if (t < 14) {
    int px = t - 7;
    float x = x1s + ((float)px + 0.5f) * bw;
    x = fminf(fmaxf(x, 0.0f), 49.0f);
    float x0 = floorf(x);
    int x0i = (int)x0;
    x0A[px] = x0i; x1A[px] = min(x0i + 1, 49); lxA[px] = x - x0;
  }
  __syncthreads();
  const float* fb = ft + (size_t)b * 2500 * 256;
  int c = t;                             // one channel per thread (CFEAT==256)
  for (int p49 = 0; p49 < 49; ++p49) {
    int py = p49 / 7, px = p49 - py * 7;
    int y0 = y0A[py], y1 = y1A[py], x0 = x0A[px], x1 = x1A[px];
    float ly = lyA[py], lx = lxA[px], hy = 1.0f - ly, hx = 1.0f - lx;
    float f00 = fb[(y0 * 50 + x0) * 256 + c];
    float f01 = fb[(y0 * 50 + x1) * 256 + c];
    float f10 = fb[(y1 * 50 + x0) * 256 + c];
    float f11 = fb[(y1 * 50 + x1) * 256 + c];
    pool[c * 49 + p49] = (hy * hx) * f00 + (hy * lx) * f01 + (ly * hx) * f10 + (ly * lx) * f11;
  }
  __syncthreads();
  float* dst = pooled + (size_t)roi * DIN;
  for (int i = t; i < DIN; i += 256) dst[i] = pool[i];
}

// ---------------- f32 GEMM, 128x128 tile, 8x8 micro, split-K via blockIdx.z ----------------
// grid: (N/128, M/128, SPLITS); 256 threads; 2 blocks/CU target.
// 8x8 microtile = 1.0 B/lane-FMA from LDS (at the ~128 B/cyc/CU LDS ceiling).
__global__ __launch_bounds__(256, 2) void k_gemm(const float* __restrict__ A, int lda,
                                                 const float* __restrict__ B, int ldb,
                                                 float* __restrict__ P, int N, int K2, int MN) {
  __shared__ float As[16][132];          // +4 pad: transpose-write conflicts 4-way -> 2-way
  __shared__ float Bs[16][128];
  int tid = threadIdx.x;
  int tx = tid & 15, ty = tid >> 4;
  int col0 = blockIdx.x << 7, row0 = blockIdx.y << 7;
  int kbeg = blockIdx.z * K2;
  const float* Ab = A + (size_t)row0 * lda + kbeg;
  const float* Bb = B + (size_t)kbeg * ldb + col0;
  int ar = tid >> 2, ak = (tid & 3) << 2;   // A: rows ar, ar+64; k-chunk ak..ak+3
  int brw = tid >> 5, bc = (tid & 31) << 2; // B: rows brw, brw+8; cols bc..bc+3
  float4 a0 = *(const float4*)(Ab + (size_t)ar * lda + ak);
  float4 a1 = *(const float4*)(Ab + (size_t)(ar + 64) * lda + ak);
  float4 b0 = *(const float4*)(Bb + (size_t)brw * ldb + bc);
  float4 b1 = *(const float4*)(Bb + (size_t)(brw + 8) * ldb + bc);
  float acc[8][8];
#pragma unroll
  for (int i = 0; i < 8; ++i)
#pragma unroll
    for (int j = 0; j < 8; ++j) acc[i][j] = 0.0f;
  for (int kt = 0; kt < K2; kt += 16) {
    __syncthreads();
    As[ak + 0][ar] = a0.x; As[ak + 1][ar] = a0.y; As[ak + 2][ar] = a0.z; As[ak + 3][ar] = a0.w;
    As[ak + 0][ar + 64] = a1.x; As[ak + 1][ar + 64] = a1.y;
    As[ak + 2][ar + 64] = a1.z; As[ak + 3][ar + 64] = a1.w;
    *(float4*)&Bs[brw][bc] = b0;
    *(float4*)&Bs[brw + 8][bc] = b1;
    __syncthreads();
    if (kt + 16 < K2) {
      a0 = *(const float4*)(Ab + (size_t)ar * lda + kt + 16 + ak);
      a1 = *(const float4*)(Ab + (size_t)(ar + 64) * lda + kt + 16 + ak);
      b0 = *(const float4*)(Bb + (size_t)(kt + 16 + brw) * ldb + bc);
      b1 = *(const float4*)(Bb + (size_t)(kt + 16 + brw + 8) * ldb + bc);
    }
#pragma unroll
    for (int kk = 0; kk < 16; ++kk) {
      float4 aL = *(const float4*)&As[kk][ty << 2];          // rows ty*4..+3 (broadcast x16)
      float4 aH = *(const float4*)&As[kk][(ty << 2) + 64];
      float4 bL = *(const float4*)&Bs[kk][tx << 2];          // cols tx*4..+3 (2-way = free)
      float4 bH = *(const float4*)&Bs[kk][(tx << 2) + 64];
      float av[8] = {aL.x, aL.y, aL.z, aL.w, aH.x, aH.y, aH.z, aH.w};
      float bv[8] = {bL.x, bL.y, bL.z, bL.w, bH.x, bH.y, bH.z, bH.w};
#pragma unroll
      for (int i = 0; i < 8; ++i)
#pragma unroll
        for (int j = 0; j < 8; ++j) acc[i][j] += av[i] * bv[j];
    }
  }
  float* Pz = P + (size_t)blockIdx.z * MN;
#pragma unroll
  for (int i = 0; i < 8; ++i) {
    int row = row0 + (ty << 2) + (i & 3) + ((i >> 2) << 6);
    float4 v0 = make_float4(acc[i][0], acc[i][1], acc[i][2], acc[i][3]);
    float4 v1 = make_float4(acc[i][4], acc[i][5], acc[i][6], acc[i][7]);
    *(float4*)(Pz + (size_t)row * N + col0 + (tx << 2)) = v0;
    *(float4*)(Pz + (size_t)row * N + col0 + (tx << 2) + 64) = v1;
  }
}

// ---------------- split-K reduce (4 partials) + bias + optional relu (float4) ----------------
__global__ void k_reduce(const float4* __restrict__ P, const float4* __restrict__ bias,
                         float4* __restrict__ out, int n4, int act) {
  int i = blockIdx.x * 256 + threadIdx.x;
  if (i >= n4) return;
  float4 p0 = P[i], p1 = P[i + n4], p2 = P[i + 2 * n4], p3 = P[i + 3 * n4];
  float4 c = bias[i & 255];
  float x = ((p0.x + p1.x) + p2.x) + p3.x + c.x;
  float y = ((p0.y + p1.y) + p2.y) + p3.y + c.y;
  float z = ((p0.z + p1.z) + p2.z) + p3.z + c.z;
  float w = ((p0.w + p1.w) + p2.w) + p3.w + c.w;
  if (act) { x = fmaxf(x, 0.f); y = fmaxf(y, 0.f); z = fmaxf(z, 0.f); w = fmaxf(w, 0.f); }
  out[i] = make_float4(x, y, z, w);
}

// ---------------- heads GEMM (cls 91 + reg 364 fused, N=455) ----------------
__global__ __launch_bounds__(256) void k_heads(const float* __restrict__ X,
                                               const float* __restrict__ Wc,
                                               const float* __restrict__ bcv,
                                               const float* __restrict__ Wr,
                                               const float* __restrict__ brv,
                                               float* __restrict__ outh) {
  __shared__ float As[16][64];
  __shared__ float Bs[16][64];
  int tid = threadIdx.x;
  int tx = tid & 15, ty = tid >> 4;
  int col0 = blockIdx.x << 6, row0 = blockIdx.y << 6;
  int ar = tid >> 2, ak = (tid & 3) << 2;
  int brw4 = (tid >> 6) << 2, bcc = tid & 63;
  int n = col0 + bcc;
  float acc[4][4];
#pragma unroll
  for (int i = 0; i < 4; ++i)
#pragma unroll
    for (int j = 0; j < 4; ++j) acc[i][j] = 0.0f;
  for (int kt = 0; kt < 1024; kt += 16) {
    float4 a0 = *(const float4*)(X + (size_t)(row0 + ar) * 1024 + kt + ak);
    float bv[4];
#pragma unroll
    for (int q = 0; q < 4; ++q) {
      int kr = kt + brw4 + q;
      bv[q] = (n < 91) ? Wc[kr * 91 + n] : ((n < 455) ? Wr[kr * 364 + (n - 91)] : 0.0f);
    }
    __syncthreads();
    As[ak + 0][ar] = a0.x; As[ak + 1][ar] = a0.y; As[ak + 2][ar] = a0.z; As[ak + 3][ar] = a0.w;
#pragma unroll
    for (int q = 0; q < 4; ++q) Bs[brw4 + q][bcc] = bv[q];
    __syncthreads();
#pragma unroll
    for (int kk = 0; kk < 16; ++kk) {
      float a4[4] = {As[kk][(ty << 2)], As[kk][(ty << 2) + 1],
                     As[kk][(ty << 2) + 2], As[kk][(ty << 2) + 3]};
      float b4[4] = {Bs[kk][(tx << 2)], Bs[kk][(tx << 2) + 1],
                     Bs[kk][(tx << 2) + 2], Bs[kk][(tx << 2) + 3]};
#pragma unroll
      for (int i = 0; i < 4; ++i)
#pragma unroll
        for (int j = 0; j < 4; ++j) acc[i][j] += a4[i] * b4[j];
    }
  }
#pragma unroll
  for (int i = 0; i < 4; ++i) {
    int row = row0 + (ty << 2) + i;
#pragma unroll
    for (int j = 0; j < 4; ++j) {
      int nn = col0 + (tx << 2) + j;
      if (nn < 455) {
        float bias = (nn < 91) ? bcv[nn] : brv[nn - 91];
        outh[(size_t)row * 455 + nn] = acc[i][j] + bias;
      }
    }
  }
}

// ---------------- softmax + decode + clip + candidate keys (one wave per roi) ----------------
__global__ __launch_bounds__(256) void k_softmax_decode(const float* __restrict__ head,
                                                        const float* __restrict__ props,
                                                        float* __restrict__ pbox,
                                                        unsigned long long* __restrict__ keys,
                                                        unsigned* __restrict__ cnt) {
  int wave = threadIdx.x >> 6, lane = threadIdx.x & 63;
  int roi = (blockIdx.x << 2) + wave;
  const float* hr = head + (size_t)roi * 455;
  float l0 = hr[lane];
  float l1 = (lane < 27) ? hr[lane + 64] : -3.4e38f;
  float m = fmaxf(l0, l1);
#pragma unroll
  for (int off = 32; off; off >>= 1) m = fmaxf(m, __shfl_xor(m, off));
  float e0 = expf(l0 - m);
  float e1 = (lane < 27) ? expf(l1 - m) : 0.0f;
  float ssum = e0 + e1;
#pragma unroll
  for (int off = 32; off; off >>= 1) ssum += __shfl_xor(ssum, off);
  const float* pr = props + (size_t)roi * 4;
  float w = pr[2] - pr[0], h = pr[3] - pr[1];
  float cx = pr[0] + 0.5f * w, cy = pr[1] + 0.5f * h;
  int img = roi >> 9, rl = roi & 511;
#pragma unroll
  for (int half = 0; half < 2; ++half) {
    int c = lane + half * 64;
    float e = half ? e1 : e0;
    if (c >= 1 && c <= 90) {
      float score = e / ssum;
      const float* rg = hr + 91 + (c << 2);
      float dx = rg[0] / 10.0f, dy = rg[1] / 10.0f;
      float dw = fminf(rg[2] / 5.0f, BBOX_CLIP_F);
      float dh = fminf(rg[3] / 5.0f, BBOX_CLIP_F);
      float pcx = dx * w + cx, pcy = dy * h + cy;
      float pw = expf(dw) * w, ph = expf(dh) * h;
      float bx1 = pcx - 0.5f * pw, by1 = pcy - 0.5f * ph;
      float bx2 = pcx + 0.5f * pw, by2 = pcy + 0.5f * ph;
      bx1 = fminf(fmaxf(bx1, 0.0f), 800.0f);
      by1 = fminf(fmaxf(by1, 0.0f), 800.0f);
      bx2 = fminf(fmaxf(bx2, 0.0f), 800.0f);
      by2 = fminf(fmaxf(by2, 0.0f), 800.0f);
      float* pb = pbox + ((size_t)roi * 90 + (c - 1)) * 4;
      pb[0] = bx1; pb[1] = by1; pb[2] = bx2; pb[3] = by2;
      if (score > 0.05f && (bx2 - bx1) >= 0.01f && (by2 - by1) >= 0.01f) {
        unsigned pos = atomicAdd(cnt + img, 1u);
        unsigned idx = (unsigned)rl * 90u + (unsigned)(c - 1);
        unsigned su = __float_as_uint(score);
        su ^= (su >> 31) ? 0xFFFFFFFFu : 0x80000000u;
        keys[((size_t)img << 14) + pos] =
            ((unsigned long long)su << 32) | (unsigned long long)(0xFFFFFFFFu - idx);
      }
    }
  }
}

// ---------------- per-image bitonic sort of candidate keys (ascending) ----------------
// one block per image; valid count <= 10240 (softmax => <=19 classes/roi over 0.05)
__global__ void k_sort(unsigned long long* __restrict__ keys, const unsigned* __restrict__ cnt) {
  extern __shared__ unsigned long long s[];
  int img = blockIdx.x, tid = threadIdx.x;
  unsigned long long* kb = keys + ((size_t)img << 14);
  unsigned n = cnt[img];
  unsigned np = 2048; while (np < n && np < 16384) np <<= 1;
  if (np <= 8192) {
    for (unsigned i = tid; i < np; i += 1024) s[i] = kb[i];
    __syncthreads();
    for (unsigned k = 2; k <= np; k <<= 1) {
      for (unsigned j = k >> 1; j; j >>= 1) {
        for (unsigned x = tid; x < (np >> 1); x += 1024) {
          unsigned i = ((x & ~(j - 1)) << 1) | (x & (j - 1));
          unsigned l = i | j;
          bool up = ((i & k) == 0);
          unsigned long long a = s[i], b = s[l];
          if ((a > b) == up) { s[i] = b; s[l] = a; }
        }
        __syncthreads();
      }
    }
    for (unsigned i = tid; i < np; i += 1024) kb[i] = s[i];
  } else {
    for (int ch = 0; ch < 2; ++ch) {
      unsigned base = (unsigned)ch << 13;
      for (unsigned i = tid; i < 8192; i += 1024) s[i] = kb[base + i];
      __syncthreads();
      for (unsigned k = 2; k <= 8192; k <<= 1) {
        for (unsigned j = k >> 1; j; j >>= 1) {
          for (unsigned x = tid; x < 4096; x += 1024) {
            unsigned i = ((x & ~(j - 1)) << 1) | (x & (j - 1));
            unsigned l = i | j;
            bool up = (((base + i) & k) == 0);
            unsigned long long a = s[i], b = s[l];
            if ((a > b) == up) { s[i] = b; s[l] = a; }
          }
          __syncthreads();
        }
      }
      for (unsigned i = tid; i < 8192; i += 1024) kb[base + i] = s[i];
      __syncthreads();
    }
    for (unsigned x = tid; x < 8192; x += 1024) {
      unsigned long long a = kb[x], b = kb[x + 8192];
      if (a > b) { kb[x] = b; kb[x + 8192] = a; }
    }
    __syncthreads();
    for (int ch = 0; ch < 2; ++ch) {
      unsigned base = (unsigned)ch << 13;
      for (unsigned i = tid; i < 8192; i += 1024) s[i] = kb[base + i];
      __syncthreads();
      for (unsigned j = 4096; j; j >>= 1) {
        for (unsigned x = tid; x < 4096; x += 1024) {
          unsigned i = ((x & ~(j - 1)) << 1) | (x & (j - 1));
          unsigned l = i | j;
          unsigned long long a = s[i], b = s[l];
          if (a > b) { s[i] = b; s[l] = a; }
        }
        __syncthreads();
      }
      for (unsigned i = tid; i < 8192; i += 1024) kb[base + i] = s[i];
      __syncthreads();
    }
  }
}

// ---------------- gather top-2048 per image into NMS arrays ----------------
__global__ void k_gather(const unsigned long long* __restrict__ keys,
                         const unsigned* __restrict__ cnt, const float* __restrict__ pbox,
                         float4* __restrict__ nmsbox, float4* __restrict__ outbox,
                         float* __restrict__ score, float* __restrict__ label) {
  int g = blockIdx.x * 256 + threadIdx.x;   // 8192
  int img = g >> 11, slot = g & 2047;
  unsigned n = cnt[img];
  unsigned neff = n > 2048u ? 2048u : n;
  unsigned np = 2048; while (np < n && np < 16384) np <<= 1;
  float4 bo = make_float4(0, 0, 0, 0), bx = make_float4(0, 0, 0, 0);
  float sc = -1.0f, lb = 0.0f;
  if ((unsigned)slot < neff) {
    unsigned long long key = keys[((size_t)img << 14) + (np - 1 - slot)];
    unsigned su = (unsigned)(key >> 32);
    su = (su & 0x80000000u) ? (su ^ 0x80000000u) : ~su;
    sc = __uint_as_float(su);
    unsigned idx = 0xFFFFFFFFu - (unsigned)(key & 0xFFFFFFFFull);
    unsigned rl = idx / 90u, c = idx - rl * 90u;
    const float* pb = pbox + ((size_t)((img << 9) + rl) * 90 + c) * 4;
    bx = *(const float4*)pb;
    float off = (float)(c + 1) * 801.0f;
    bo = make_float4(bx.x + off, bx.y + off, bx.z + off, bx.w + off);
    lb = (float)(c + 1);
  }
  nmsbox[g] = bo; outbox[g] = bx; score[g] = sc; label[g] = lb;
}

// ---------------- IoU bitmask: mask[img][i][w] bits j=32w..32w+31 ----------------
__global__ __launch_bounds__(256) void k_mask(const float* __restrict__ nmsbox,
                                              unsigned* __restrict__ mask) {
  __shared__ float bx[2048 * 4];
  int img = blockIdx.x >> 9;
  int i0 = (blockIdx.x & 511) << 2;
  const float4* src = (const float4*)(nmsbox + (size_t)img * 2048 * 4);
  for (int q = threadIdx.x; q < 2048; q += 256) ((float4*)bx)[q] = src[q];
  __syncthreads();
  int w = threadIdx.x & 63, ir = threadIdx.x >> 6;
  int i = i0 + ir;
  float ax1 = bx[i * 4], ay1 = bx[i * 4 + 1], ax2 = bx[i * 4 + 2], ay2 = bx[i * 4 + 3];
  float areaA = (ax2 - ax1) * (ay2 - ay1);
  unsigned bits = 0;
  for (int jj = 0; jj < 32; ++jj) {
    int j2 = (jj + w) & 31;                 // rotate for LDS bank spread
    int j = (w << 5) + j2;
    float b1 = bx[j * 4], b2 = bx[j * 4 + 1], b3 = bx[j * 4 + 2], b4 = bx[j * 4 + 3];
    float areaB = (b3 - b1) * (b4 - b2);
    float lx = fmaxf(ax1, b1), lyv = fmaxf(ay1, b2);
    float rx = fminf(ax2, b3), ry = fminf(ay2, b4);
    float iw = fmaxf(rx - lx, 0.0f), ih = fmaxf(ry - lyv, 0.0f);
    float inter = iw * ih;
    float iou = inter / (areaA + areaB - inter);
    if (iou > 0.5f) bits |= (1u << j2);
  }
  mask[((size_t)img * 2048 + i) * 64 + w] = bits;
}

// ---------------- sequential greedy NMS scan + direct output emit (1 wave/image) ----------------
__global__ void k_scan(const unsigned* __restrict__ mask, const unsigned* __restrict__ cnt,
                       const float* __restrict__ outbox, const float* __restrict__ score,
                       const float* __restrict__ label, float* __restrict__ dout) {
  int img = blockIdx.x, lane = threadIdx.x;   // 64 threads
  unsigned n = cnt[img];
  unsigned neff = n > 2048u ? 2048u : n;
  unsigned base = (unsigned)lane * 32u;
  unsigned rem;
  if (base + 32u <= neff) rem = 0u;
  else if (base >= neff) rem = 0xFFFFFFFFu;
  else rem = ~((1u << (neff - base)) - 1u);
  const unsigned* mrow = mask + (size_t)img * 2048 * 64;
  unsigned row = (neff > 0) ? mrow[lane] : 0u;
  int outc = 0;
  for (int i = 0; i < (int)neff; ++i) {
    unsigned nextrow = (i + 1 < (int)neff) ? mrow[(size_t)(i + 1) * 64 + lane] : 0u;
    unsigned wrd = __shfl(rem, i >> 5);
    bool kept = ((wrd >> (i & 31)) & 1u) == 0u;
    if (kept) {
      rem |= row;
      if (lane < 4)
        dout[(size_t)(img * 100 + outc) * 4 + lane] = outbox[((size_t)img * 2048 + i) * 4 + lane];
      if (lane == 0) {
        dout[1600 + img * 100 + outc] = score[img * 2048 + i];
        dout[2000 + img * 100 + outc] = label[img * 2048 + i];
      }
      ++outc;
      if (outc >= 100) break;
    }
    row = nextrow;
  }
}

// ---------------- host launch ----------------
extern "C" void kernel_launch(void* const* d_in, const int* in_sizes, int n_in,
                              void* d_out, int out_size, void* d_ws, size_t ws_size,
                              hipStream_t stream) {
  if (ws_size < O_END) return;   // diagnostic: will show as "0 nodes" if ws too small

  const float* features  = (const float*)d_in[0];
  const float* proposals = (const float*)d_in[1];
  const float* W1 = (const float*)d_in[2];
  const float* b1 = (const float*)d_in[3];
  const float* W2 = (const float*)d_in[4];
  const float* b2 = (const float*)d_in[5];
  const float* Wc = (const float*)d_in[6];
  const float* bc = (const float*)d_in[7];
  const float* Wr = (const float*)d_in[8];
  const float* br = (const float*)d_in[9];
  float* out = (float*)d_out;
  char* ws = (char*)d_ws;

  float* featT  = (float*)(ws + O_FEATT);
  float* pooled = (float*)(ws + O_POOLED);
  float* part   = (float*)(ws + O_PART);
  float* x1     = (float*)(ws + O_X1);
  float* x2     = (float*)(ws + O_X2);
  float* head   = (float*)(ws + O_HEAD);
  float* pbox   = (float*)(ws + O_PBOX);
  unsigned long long* keys = (unsigned long long*)(ws + O_KEYS);
  float* nmsbox = (float*)(ws + O_NMSBOX);
  float* outbox = (float*)(ws + O_OUTBOX);
  float* scorea = (float*)(ws + O_SCORE);
  float* labela = (float*)(ws + O_LABEL);
  unsigned* maska = (unsigned*)(ws + O_MASK);
  unsigned* cnt = (unsigned*)(ws + O_CNT);

  k_zero<<<512, 256, 0, stream>>>(out, (unsigned*)keys, cnt);
  k_transpose<<<10000, 256, 0, stream>>>(features, featT);
  k_roialign<<<2048, 256, 0, stream>>>(featT, proposals, pooled);
  // FC1: [2048,12544] @ [12544,1024], split-K = 4 x 3136; 512 blocks = 2/CU
  k_gemm<<<dim3(8, 16, 4), 256, 0, stream>>>(pooled, 12544, W1, 1024, part, 1024, 3136,
                                             2048 * 1024);
  k_reduce<<<2048, 256, 0, stream>>>((const float4*)part, (const float4*)b1, (float4*)x1,
                                     524288, 1);
  // FC2: [2048,1024] @ [1024,1024], split-K = 4 x 256
  k_gemm<<<dim3(8, 16, 4), 256, 0, stream>>>(x1, 1024, W2, 1024, part, 1024, 256,
                                             2048 * 1024);
  k_reduce<<<2048, 256, 0, stream>>>((const float4*)part, (const float4*)b2, (float4*)x2,
                                     524288, 1);   // x2 aliases part[0]: in-place safe
  k_heads<<<dim3(8, 32), 256, 0, stream>>>(x2, Wc, bc, Wr, br, head);
  k_softmax_decode<<<512, 256, 0, stream>>>(head, proposals, pbox, keys, cnt);
  k_sort<<<4, 1024, 65536, stream>>>(keys, cnt);
  k_gather<<<32, 256, 0, stream>>>(keys, cnt, pbox, (float4*)nmsbox, (float4*)outbox,
                                   scorea, labela);
  k_mask<<<2048, 256, 0, stream>>>(nmsbox, maska);
  k_scan<<<4, 64, 0, stream>>>(maska, cnt, outbox, scorea, labela, out);
}

// Round 4
// 966.710 us; speedup vs baseline: 1.0657x; 1.0657x over previous
//
#include <hip/hip_runtime.h>
#include <stdint.h>

// ---------------- problem constants ----------------
#define NBI 4          // batch
#define RRI 512        // rois per image
#define NROI 2048      // NBI*RRI
#define CFEAT 256
#define HF 50
#define WF 50
#define NCLS 91
#define DIN 12544      // 256*7*7
#define H1 1024
#define NHEAD 455      // 91 + 4*91
#define TOPK 2048
#define DETS 100

// ---------------- workspace layout (bytes) ----------------
#define O_FEATT   0ull                    // 10,240,000  [4][50][50][256] f32
#define O_POOLED  10240000ull             // 102,760,448 [2048][12544] f32
#define O_PART    113000448ull             // 33,554,432  [4][2048][1024] f32 (also x2 later)
#define O_X1      0ull                    // reuses featT region (8,388,608)
#define O_X2      113000448ull            // aliases PART p0 (in-place reduce)
#define O_HEAD    146554880ull            // 3,727,360   [2048][455] f32
#define O_PBOX    150282240ull            // 2,949,120   [2048][90][4] f32 (clipped boxes)
#define O_KEYS    153231360ull            // 524,288     [4][16384] u64
#define O_NMSBOX  153755648ull            // 131,072     [4][2048][4] f32 (offset boxes)
#define O_OUTBOX  153886720ull            // 131,072     [4][2048][4] f32 (clipped boxes)
#define O_SCORE   154017792ull            // 32,768      [4][2048] f32
#define O_LABEL   154050560ull            // 32,768      [4][2048] f32
#define O_MASK    154083328ull            // 2,097,152   [4][2048][64] u32
#define O_CNT     156180480ull            // 256         [4] u32
#define O_END     156180736ull

#define BBOX_CLIP_F 4.135166556742356f    // float(log(1000/16))

// ---------------- zero init (d_out, keys, counters) ----------------
__global__ void k_zero(float* __restrict__ out, unsigned* __restrict__ keys32,
                       unsigned* __restrict__ cnt) {
  int i = blockIdx.x * 256 + threadIdx.x;
  if (i < 2400) out[i] = 0.0f;
  if (i < 131072) keys32[i] = 0u;      // 4*16384 u64 = 131072 u32
  if (i < 64) cnt[i] = 0u;
}

// ---------------- features [B,C,H,W] -> [B,H,W,C] ----------------
__global__ void k_transpose(const float* __restrict__ f, float* __restrict__ ft) {
  int bhw = blockIdx.x;                  // b*2500 + h*50 + w  (grid 10000)
  int c = threadIdx.x;                   // 256
  int b = bhw / 2500, hw = bhw - b * 2500;
  ft[(size_t)bhw * 256 + c] = f[((size_t)b * 256 + c) * 2500 + hw];
}

// ---------------- RoI align: one block per roi ----------------
__global__ __launch_bounds__(256) void k_roialign(const float* __restrict__ ft,
                                                  const float* __restrict__ props,
                                                  float* __restrict__ pooled) {
  __shared__ float pool[DIN];
  __shared__ float lyA[7], lxA[7];
  __shared__ int y0A[7], y1A[7], x0A[7], x1A[7];
  int roi = blockIdx.x;
  int b = roi >> 9;
  const float* p = props + (size_t)roi * 4;
  float x1s = p[0] * 0.0625f, y1s = p[1] * 0.0625f;
  float x2s = p[2] * 0.0625f, y2s = p[3] * 0.0625f;
  float bh = (y2s - y1s) / 7.0f;
  float bw = (x2s - x1s) / 7.0f;
  int t = threadIdx.x;
  if (t < 7) {
    float y = y1s + ((float)t + 0.5f) * bh;
    y = fminf(fmaxf(y, 0.0f), 49.0f);
    float y0 = floorf(y);
    int y0i = (int)y0;
    y0A[t] = y0i; y1A[t] = min(y0i + 1, 49); lyA[t] = y - y0;
  } else if (t < 14) {
    int px = t - 7;
    float x = x1s + ((float)px + 0.5f) * bw;
    x = fminf(fmaxf(x, 0.0f), 49.0f);
    float x0 = floorf(x);
    int x0i = (int)x0;
    x0A[px] = x0i; x1A[px] = min(x0i + 1, 49); lxA[px] = x - x0;
  }
  __syncthreads();
  const float* fb = ft + (size_t)b * 2500 * 256;
  int c = t;                             // one channel per thread (CFEAT==256)
  for (int p49 = 0; p49 < 49; ++p49) {
    int py = p49 / 7, px = p49 - py * 7;
    int y0 = y0A[py], y1 = y1A[py], x0 = x0A[px], x1 = x1A[px];
    float ly = lyA[py], lx = lxA[px], hy = 1.0f - ly, hx = 1.0f - lx;
    float f00 = fb[(y0 * 50 + x0) * 256 + c];
    float f01 = fb[(y0 * 50 + x1) * 256 + c];
    float f10 = fb[(y1 * 50 + x0) * 256 + c];
    float f11 = fb[(y1 * 50 + x1) * 256 + c];
    pool[c * 49 + p49] = (hy * hx) * f00 + (hy * lx) * f01 + (ly * hx) * f10 + (ly * lx) * f11;
  }
  __syncthreads();
  float* dst = pooled + (size_t)roi * DIN;
  for (int i = t; i < DIN; i += 256) dst[i] = pool[i];
}

// ---------------- f32 GEMM, 128x64 tile, 8x4 micro, split-K via blockIdx.z ----------------
// grid: (N/64, M/128, SPLITS); 256 threads; VGPR=48 -> grid-limited occupancy,
// so SPLITS=4 gives 1024 blocks = 4 blocks/CU = 4 waves/SIMD (latency hiding).
__global__ __launch_bounds__(256) void k_gemm(const float* __restrict__ A, int lda,
                                              const float* __restrict__ B, int ldb,
                                              float* __restrict__ P, int N, int K2, int MN) {
  __shared__ float As[16][132];          // +4 pad: transpose-write conflicts 4-way -> 2-way
  __shared__ float Bs[16][64];
  int tid = threadIdx.x;
  int tx = tid & 15, ty = tid >> 4;
  int col0 = blockIdx.x << 6, row0 = blockIdx.y << 7;
  int kbeg = blockIdx.z * K2;
  const float* Ab = A + (size_t)row0 * lda + kbeg;
  const float* Bb = B + (size_t)kbeg * ldb + col0;
  int ar = tid >> 2, ak = (tid & 3) << 2;   // A: rows ar, ar+64; k-chunk ak..ak+3
  int brw = tid >> 4, bc = (tid & 15) << 2; // B: row brw (0..15), cols bc..bc+3
  float4 a0 = *(const float4*)(Ab + (size_t)ar * lda + ak);
  float4 a1 = *(const float4*)(Ab + (size_t)(ar + 64) * lda + ak);
  float4 b0 = *(const float4*)(Bb + (size_t)brw * ldb + bc);
  float acc[8][4];
#pragma unroll
  for (int i = 0; i < 8; ++i)
#pragma unroll
    for (int j = 0; j < 4; ++j) acc[i][j] = 0.0f;
  for (int kt = 0; kt < K2; kt += 16) {
    __syncthreads();
    As[ak + 0][ar] = a0.x; As[ak + 1][ar] = a0.y; As[ak + 2][ar] = a0.z; As[ak + 3][ar] = a0.w;
    As[ak + 0][ar + 64] = a1.x; As[ak + 1][ar + 64] = a1.y;
    As[ak + 2][ar + 64] = a1.z; As[ak + 3][ar + 64] = a1.w;
    *(float4*)&Bs[brw][bc] = b0;
    __syncthreads();
    if (kt + 16 < K2) {
      a0 = *(const float4*)(Ab + (size_t)ar * lda + kt + 16 + ak);
      a1 = *(const float4*)(Ab + (size_t)(ar + 64) * lda + kt + 16 + ak);
      b0 = *(const float4*)(Bb + (size_t)(kt + 16 + brw) * ldb + bc);
    }
#pragma unroll
    for (int kk = 0; kk < 16; ++kk) {
      float4 aL = *(const float4*)&As[kk][ty << 2];          // rows ty*4..+3 (broadcast)
      float4 aH = *(const float4*)&As[kk][(ty << 2) + 64];   // rows 64+ty*4..+3
      float4 bL = *(const float4*)&Bs[kk][tx << 2];          // cols tx*4..+3
      float av[8] = {aL.x, aL.y, aL.z, aL.w, aH.x, aH.y, aH.z, aH.w};
      float bv[4] = {bL.x, bL.y, bL.z, bL.w};
#pragma unroll
      for (int i = 0; i < 8; ++i)
#pragma unroll
        for (int j = 0; j < 4; ++j) acc[i][j] += av[i] * bv[j];
    }
  }
  float* Pz = P + (size_t)blockIdx.z * MN;
#pragma unroll
  for (int i = 0; i < 8; ++i) {
    int row = row0 + (ty << 2) + (i & 3) + ((i >> 2) << 6);
    float4 v0 = make_float4(acc[i][0], acc[i][1], acc[i][2], acc[i][3]);
    *(float4*)(Pz + (size_t)row * N + col0 + (tx << 2)) = v0;
  }
}

// ---------------- split-K reduce (4 partials) + bias + optional relu (float4) ----------------
__global__ void k_reduce(const float4* __restrict__ P, const float4* __restrict__ bias,
                         float4* __restrict__ out, int n4, int act) {
  int i = blockIdx.x * 256 + threadIdx.x;
  if (i >= n4) return;
  float4 p0 = P[i], p1 = P[i + n4], p2 = P[i + 2 * n4], p3 = P[i + 3 * n4];
  float4 c = bias[i & 255];
  float x = ((p0.x + p1.x) + p2.x) + p3.x + c.x;
  float y = ((p0.y + p1.y) + p2.y) + p3.y + c.y;
  float z = ((p0.z + p1.z) + p2.z) + p3.z + c.z;
  float w = ((p0.w + p1.w) + p2.w) + p3.w + c.w;
  if (act) { x = fmaxf(x, 0.f); y = fmaxf(y, 0.f); z = fmaxf(z, 0.f); w = fmaxf(w, 0.f); }
  out[i] = make_float4(x, y, z, w);
}

// ---------------- heads GEMM (cls 91 + reg 364 fused, N=455) ----------------
__global__ __launch_bounds__(256) void k_heads(const float* __restrict__ X,
                                               const float* __restrict__ Wc,
                                               const float* __restrict__ bcv,
                                               const float* __restrict__ Wr,
                                               const float* __restrict__ brv,
                                               float* __restrict__ outh) {
  __shared__ float As[16][64];
  __shared__ float Bs[16][64];
  int tid = threadIdx.x;
  int tx = tid & 15, ty = tid >> 4;
  int col0 = blockIdx.x << 6, row0 = blockIdx.y << 6;
  int ar = tid >> 2, ak = (tid & 3) << 2;
  int brw4 = (tid >> 6) << 2, bcc = tid & 63;
  int n = col0 + bcc;
  float acc[4][4];
#pragma unroll
  for (int i = 0; i < 4; ++i)
#pragma unroll
    for (int j = 0; j < 4; ++j) acc[i][j] = 0.0f;
  for (int kt = 0; kt < 1024; kt += 16) {
    float4 a0 = *(const float4*)(X + (size_t)(row0 + ar) * 1024 + kt + ak);
    float bv[4];
#pragma unroll
    for (int q = 0; q < 4; ++q) {
      int kr = kt + brw4 + q;
      bv[q] = (n < 91) ? Wc[kr * 91 + n] : ((n < 455) ? Wr[kr * 364 + (n - 91)] : 0.0f);
    }
    __syncthreads();
    As[ak + 0][ar] = a0.x; As[ak + 1][ar] = a0.y; As[ak + 2][ar] = a0.z; As[ak + 3][ar] = a0.w;
#pragma unroll
    for (int q = 0; q < 4; ++q) Bs[brw4 + q][bcc] = bv[q];
    __syncthreads();
#pragma unroll
    for (int kk = 0; kk < 16; ++kk) {
      float a4[4] = {As[kk][(ty << 2)], As[kk][(ty << 2) + 1],
                     As[kk][(ty << 2) + 2], As[kk][(ty << 2) + 3]};
      float b4[4] = {Bs[kk][(tx << 2)], Bs[kk][(tx << 2) + 1],
                     Bs[kk][(tx << 2) + 2], Bs[kk][(tx << 2) + 3]};
#pragma unroll
      for (int i = 0; i < 4; ++i)
#pragma unroll
        for (int j = 0; j < 4; ++j) acc[i][j] += a4[i] * b4[j];
    }
  }
#pragma unroll
  for (int i = 0; i < 4; ++i) {
    int row = row0 + (ty << 2) + i;
#pragma unroll
    for (int j = 0; j < 4; ++j) {
      int nn = col0 + (tx << 2) + j;
      if (nn < 455) {
        float bias = (nn < 91) ? bcv[nn] : brv[nn - 91];
        outh[(size_t)row * 455 + nn] = acc[i][j] + bias;
      }
    }
  }
}

// ---------------- softmax + decode + clip + candidate keys (one wave per roi) ----------------
__global__ __launch_bounds__(256) void k_softmax_decode(const float* __restrict__ head,
                                                        const float* __restrict__ props,
                                                        float* __restrict__ pbox,
                                                        unsigned long long* __restrict__ keys,
                                                        unsigned* __restrict__ cnt) {
  int wave = threadIdx.x >> 6, lane = threadIdx.x & 63;
  int roi = (blockIdx.x << 2) + wave;
  const float* hr = head + (size_t)roi * 455;
  float l0 = hr[lane];
  float l1 = (lane < 27) ? hr[lane + 64] : -3.4e38f;
  float m = fmaxf(l0, l1);
#pragma unroll
  for (int off = 32; off; off >>= 1) m = fmaxf(m, __shfl_xor(m, off));
  float e0 = expf(l0 - m);
  float e1 = (lane < 27) ? expf(l1 - m) : 0.0f;
  float ssum = e0 + e1;
#pragma unroll
  for (int off = 32; off; off >>= 1) ssum += __shfl_xor(ssum, off);
  const float* pr = props + (size_t)roi * 4;
  float w = pr[2] - pr[0], h = pr[3] - pr[1];
  float cx = pr[0] + 0.5f * w, cy = pr[1] + 0.5f * h;
  int img = roi >> 9, rl = roi & 511;
#pragma unroll
  for (int half = 0; half < 2; ++half) {
    int c = lane + half * 64;
    float e = half ? e1 : e0;
    if (c >= 1 && c <= 90) {
      float score = e / ssum;
      const float* rg = hr + 91 + (c << 2);
      float dx = rg[0] / 10.0f, dy = rg[1] / 10.0f;
      float dw = fminf(rg[2] / 5.0f, BBOX_CLIP_F);
      float dh = fminf(rg[3] / 5.0f, BBOX_CLIP_F);
      float pcx = dx * w + cx, pcy = dy * h + cy;
      float pw = expf(dw) * w, ph = expf(dh) * h;
      float bx1 = pcx - 0.5f * pw, by1 = pcy - 0.5f * ph;
      float bx2 = pcx + 0.5f * pw, by2 = pcy + 0.5f * ph;
      bx1 = fminf(fmaxf(bx1, 0.0f), 800.0f);
      by1 = fminf(fmaxf(by1, 0.0f), 800.0f);
      bx2 = fminf(fmaxf(bx2, 0.0f), 800.0f);
      by2 = fminf(fmaxf(by2, 0.0f), 800.0f);
      float* pb = pbox + ((size_t)roi * 90 + (c - 1)) * 4;
      pb[0] = bx1; pb[1] = by1; pb[2] = bx2; pb[3] = by2;
      if (score > 0.05f && (bx2 - bx1) >= 0.01f && (by2 - by1) >= 0.01f) {
        unsigned pos = atomicAdd(cnt + img, 1u);
        unsigned idx = (unsigned)rl * 90u + (unsigned)(c - 1);
        unsigned su = __float_as_uint(score);
        su ^= (su >> 31) ? 0xFFFFFFFFu : 0x80000000u;
        keys[((size_t)img << 14) + pos] =
            ((unsigned long long)su << 32) | (unsigned long long)(0xFFFFFFFFu - idx);
      }
    }
  }
}

// ---------------- per-image bitonic sort of candidate keys (ascending) ----------------
// one block per image; valid count <= 10240 (softmax => <=19 classes/roi over 0.05)
__global__ void k_sort(unsigned long long* __restrict__ keys, const unsigned* __restrict__ cnt) {
  extern __shared__ unsigned long long s[];
  int img = blockIdx.x, tid = threadIdx.x;
  unsigned long long* kb = keys + ((size_t)img << 14);
  unsigned n = cnt[img];
  unsigned np = 2048; while (np < n && np < 16384) np <<= 1;
  if (np <= 8192) {
    for (unsigned i = tid; i < np; i += 1024) s[i] = kb[i];
    __syncthreads();
    for (unsigned k = 2; k <= np; k <<= 1) {
      for (unsigned j = k >> 1; j; j >>= 1) {
        for (unsigned x = tid; x < (np >> 1); x += 1024) {
          unsigned i = ((x & ~(j - 1)) << 1) | (x & (j - 1));
          unsigned l = i | j;
          bool up = ((i & k) == 0);
          unsigned long long a = s[i], b = s[l];
          if ((a > b) == up) { s[i] = b; s[l] = a; }
        }
        __syncthreads();
      }
    }
    for (unsigned i = tid; i < np; i += 1024) kb[i] = s[i];
  } else {
    for (int ch = 0; ch < 2; ++ch) {
      unsigned base = (unsigned)ch << 13;
      for (unsigned i = tid; i < 8192; i += 1024) s[i] = kb[base + i];
      __syncthreads();
      for (unsigned k = 2; k <= 8192; k <<= 1) {
        for (unsigned j = k >> 1; j; j >>= 1) {
          for (unsigned x = tid; x < 4096; x += 1024) {
            unsigned i = ((x & ~(j - 1)) << 1) | (x & (j - 1));
            unsigned l = i | j;
            bool up = (((base + i) & k) == 0);
            unsigned long long a = s[i], b = s[l];
            if ((a > b) == up) { s[i] = b; s[l] = a; }
          }
          __syncthreads();
        }
      }
      for (unsigned i = tid; i < 8192; i += 1024) kb[base + i] = s[i];
      __syncthreads();
    }
    for (unsigned x = tid; x < 8192; x += 1024) {
      unsigned long long a = kb[x], b = kb[x + 8192];
      if (a > b) { kb[x] = b; kb[x + 8192] = a; }
    }
    __syncthreads();
    for (int ch = 0; ch < 2; ++ch) {
      unsigned base = (unsigned)ch << 13;
      for (unsigned i = tid; i < 8192; i += 1024) s[i] = kb[base + i];
      __syncthreads();
      for (unsigned j = 4096; j; j >>= 1) {
        for (unsigned x = tid; x < 4096; x += 1024) {
          unsigned i = ((x & ~(j - 1)) << 1) | (x & (j - 1));
          unsigned l = i | j;
          unsigned long long a = s[i], b = s[l];
          if (a > b) { s[i] = b; s[l] = a; }
        }
        __syncthreads();
      }
      for (unsigned i = tid; i < 8192; i += 1024) kb[base + i] = s[i];
      __syncthreads();
    }
  }
}

// ---------------- gather top-2048 per image into NMS arrays ----------------
__global__ void k_gather(const unsigned long long* __restrict__ keys,
                         const unsigned* __restrict__ cnt, const float* __restrict__ pbox,
                         float4* __restrict__ nmsbox, float4* __restrict__ outbox,
                         float* __restrict__ score, float* __restrict__ label) {
  int g = blockIdx.x * 256 + threadIdx.x;   // 8192
  int img = g >> 11, slot = g & 2047;
  unsigned n = cnt[img];
  unsigned neff = n > 2048u ? 2048u : n;
  unsigned np = 2048; while (np < n && np < 16384) np <<= 1;
  float4 bo = make_float4(0, 0, 0, 0), bx = make_float4(0, 0, 0, 0);
  float sc = -1.0f, lb = 0.0f;
  if ((unsigned)slot < neff) {
    unsigned long long key = keys[((size_t)img << 14) + (np - 1 - slot)];
    unsigned su = (unsigned)(key >> 32);
    su = (su & 0x80000000u) ? (su ^ 0x80000000u) : ~su;
    sc = __uint_as_float(su);
    unsigned idx = 0xFFFFFFFFu - (unsigned)(key & 0xFFFFFFFFull);
    unsigned rl = idx / 90u, c = idx - rl * 90u;
    const float* pb = pbox + ((size_t)((img << 9) + rl) * 90 + c) * 4;
    bx = *(const float4*)pb;
    float off = (float)(c + 1) * 801.0f;
    bo = make_float4(bx.x + off, bx.y + off, bx.z + off, bx.w + off);
    lb = (float)(c + 1);
  }
  nmsbox[g] = bo; outbox[g] = bx; score[g] = sc; label[g] = lb;
}

// ---------------- IoU bitmask: mask[img][i][w] bits j=32w..32w+31 ----------------
__global__ __launch_bounds__(256) void k_mask(const float* __restrict__ nmsbox,
                                              unsigned* __restrict__ mask) {
  __shared__ float bx[2048 * 4];
  int img = blockIdx.x >> 9;
  int i0 = (blockIdx.x & 511) << 2;
  const float4* src = (const float4*)(nmsbox + (size_t)img * 2048 * 4);
  for (int q = threadIdx.x; q < 2048; q += 256) ((float4*)bx)[q] = src[q];
  __syncthreads();
  int w = threadIdx.x & 63, ir = threadIdx.x >> 6;
  int i = i0 + ir;
  float ax1 = bx[i * 4], ay1 = bx[i * 4 + 1], ax2 = bx[i * 4 + 2], ay2 = bx[i * 4 + 3];
  float areaA = (ax2 - ax1) * (ay2 - ay1);
  unsigned bits = 0;
  for (int jj = 0; jj < 32; ++jj) {
    int j2 = (jj + w) & 31;                 // rotate for LDS bank spread
    int j = (w << 5) + j2;
    float b1 = bx[j * 4], b2 = bx[j * 4 + 1], b3 = bx[j * 4 + 2], b4 = bx[j * 4 + 3];
    float areaB = (b3 - b1) * (b4 - b2);
    float lx = fmaxf(ax1, b1), lyv = fmaxf(ay1, b2);
    float rx = fminf(ax2, b3), ry = fminf(ay2, b4);
    float iw = fmaxf(rx - lx, 0.0f), ih = fmaxf(ry - lyv, 0.0f);
    float inter = iw * ih;
    float iou = inter / (areaA + areaB - inter);
    if (iou > 0.5f) bits |= (1u << j2);
  }
  mask[((size_t)img * 2048 + i) * 64 + w] = bits;
}

// ---------------- sequential greedy NMS scan + direct output emit (1 wave/image) ----------------
__global__ void k_scan(const unsigned* __restrict__ mask, const unsigned* __restrict__ cnt,
                       const float* __restrict__ outbox, const float* __restrict__ score,
                       const float* __restrict__ label, float* __restrict__ dout) {
  int img = blockIdx.x, lane = threadIdx.x;   // 64 threads
  unsigned n = cnt[img];
  unsigned neff = n > 2048u ? 2048u : n;
  unsigned base = (unsigned)lane * 32u;
  unsigned rem;
  if (base + 32u <= neff) rem = 0u;
  else if (base >= neff) rem = 0xFFFFFFFFu;
  else rem = ~((1u << (neff - base)) - 1u);
  const unsigned* mrow = mask + (size_t)img * 2048 * 64;
  unsigned row = (neff > 0) ? mrow[lane] : 0u;
  int outc = 0;
  for (int i = 0; i < (int)neff; ++i) {
    unsigned nextrow = (i + 1 < (int)neff) ? mrow[(size_t)(i + 1) * 64 + lane] : 0u;
    unsigned wrd = __shfl(rem, i >> 5);
    bool kept = ((wrd >> (i & 31)) & 1u) == 0u;
    if (kept) {
      rem |= row;
      if (lane < 4)
        dout[(size_t)(img * 100 + outc) * 4 + lane] = outbox[((size_t)img * 2048 + i) * 4 + lane];
      if (lane == 0) {
        dout[1600 + img * 100 + outc] = score[img * 2048 + i];
        dout[2000 + img * 100 + outc] = label[img * 2048 + i];
      }
      ++outc;
      if (outc >= 100) break;
    }
    row = nextrow;
  }
}

// ---------------- host launch ----------------
extern "C" void kernel_launch(void* const* d_in, const int* in_sizes, int n_in,
                              void* d_out, int out_size, void* d_ws, size_t ws_size,
                              hipStream_t stream) {
  if (ws_size < O_END) return;   // diagnostic: will show as "0 nodes" if ws too small

  const float* features  = (const float*)d_in[0];
  const float* proposals = (const float*)d_in[1];
  const float* W1 = (const float*)d_in[2];
  const float* b1 = (const float*)d_in[3];
  const float* W2 = (const float*)d_in[4];
  const float* b2 = (const float*)d_in[5];
  const float* Wc = (const float*)d_in[6];
  const float* bc = (const float*)d_in[7];
  const float* Wr = (const float*)d_in[8];
  const float* br = (const float*)d_in[9];
  float* out = (float*)d_out;
  char* ws = (char*)d_ws;

  float* featT  = (float*)(ws + O_FEATT);
  float* pooled = (float*)(ws + O_POOLED);
  float* part   = (float*)(ws + O_PART);
  float* x1     = (float*)(ws + O_X1);
  float* x2     = (float*)(ws + O_X2);
  float* head   = (float*)(ws + O_HEAD);
  float* pbox   = (float*)(ws + O_PBOX);
  unsigned long long* keys = (unsigned long long*)(ws + O_KEYS);
  float* nmsbox = (float*)(ws + O_NMSBOX);
  float* outbox = (float*)(ws + O_OUTBOX);
  float* scorea = (float*)(ws + O_SCORE);
  float* labela = (float*)(ws + O_LABEL);
  unsigned* maska = (unsigned*)(ws + O_MASK);
  unsigned* cnt = (unsigned*)(ws + O_CNT);

  k_zero<<<512, 256, 0, stream>>>(out, (unsigned*)keys, cnt);
  k_transpose<<<10000, 256, 0, stream>>>(features, featT);
  k_roialign<<<2048, 256, 0, stream>>>(featT, proposals, pooled);
  // FC1: [2048,12544] @ [12544,1024], split-K = 4 x 3136; 1024 blocks = 4/CU
  k_gemm<<<dim3(16, 16, 4), 256, 0, stream>>>(pooled, 12544, W1, 1024, part, 1024, 3136,
                                              2048 * 1024);
  k_reduce<<<2048, 256, 0, stream>>>((const float4*)part, (const float4*)b1, (float4*)x1,
                                     524288, 1);
  // FC2: [2048,1024] @ [1024,1024], split-K = 4 x 256
  k_gemm<<<dim3(16, 16, 4), 256, 0, stream>>>(x1, 1024, W2, 1024, part, 1024, 256,
                                              2048 * 1024);
  k_reduce<<<2048, 256, 0, stream>>>((const float4*)part, (const float4*)b2, (float4*)x2,
                                     524288, 1);   // x2 aliases part[0]: in-place safe
  k_heads<<<dim3(8, 32), 256, 0, stream>>>(x2, Wc, bc, Wr, br, head);
  k_softmax_decode<<<512, 256, 0, stream>>>(head, proposals, pbox, keys, cnt);
  k_sort<<<4, 1024, 65536, stream>>>(keys, cnt);
  k_gather<<<32, 256, 0, stream>>>(keys, cnt, pbox, (float4*)nmsbox, (float4*)outbox,
                                   scorea, labela);
  k_mask<<<2048, 256, 0, stream>>>(nmsbox, maska);
  k_scan<<<4, 64, 0, stream>>>(maska, cnt, outbox, scorea, labela, out);
}